// Round 10
// baseline (67.521 us; speedup 1.0000x reference)
//
#include <hip/hip_runtime.h>
#include <hip/hip_bf16.h>
#include <hip/hip_cooperative_groups.h>

namespace cg = cooperative_groups;

typedef __attribute__((ext_vector_type(8))) short bf16x8;
typedef __attribute__((ext_vector_type(4))) float f32x4;
typedef __attribute__((ext_vector_type(4))) int   i32x4;

// ---------------------------------------------------------------------------
// B=2, C=64, H=W=64, N=4096, dk=8.
// Sobel weights are broadcast over [C,C,3,3] -> conv output = conv(chansum).
// Keys/queries affine in scalar field e[n]; softmax row m = softmax_n(t_m*e[n]),
// t_m = alpha*eq[m]+gamma; row max = t*e_max (t>0) else t*e_min.
// SINGLE cooperative node: phase1 (value GEMM + s byproduct + alpha/gamma)
//   -> grid.sync() -> phase3 (per-block sobel recompute + full-K attention).
// R6 lesson: ad-hoc cross-block fences are poison; grid.sync is the one
// sanctioned barrier and costs ~a kernel boundary.
// R9 lesson: kernels are ~12-14us total; graph-node dispatch is the rest.
// ---------------------------------------------------------------------------

#define CH 512
#define NCH 8

__global__ __launch_bounds__(512, 2) void kAll(
    const float* __restrict__ vi, const float* __restrict__ ir,
    const float* __restrict__ wsx_vi, const float* __restrict__ wsy_vi,
    const float* __restrict__ wsx_q,  const float* __restrict__ wsy_q,
    const float* __restrict__ wsx_ir, const float* __restrict__ wsy_ir,
    const float* __restrict__ w1_vi, const float* __restrict__ w1_q,
    const float* __restrict__ b1_q,  const float* __restrict__ w1_ir,
    const float* __restrict__ wv_vi, const float* __restrict__ bv_vi,
    const float* __restrict__ wv_ir, const float* __restrict__ bv_ir,
    float* __restrict__ s, __hip_bfloat16* __restrict__ Vc,
    float* __restrict__ out) {
    __shared__ __align__(16) char vbuf[2][64 * CH * 2];  // 2 x 64 KB
    __shared__ __align__(16) float elds[4096];           // 16 KB
    __shared__ float mm[16];
    __shared__ float agA[8], agC[8], agB[8];

    const int bid = blockIdx.x;
    const int tid = threadIdx.x;
    const int wvw = tid >> 6, lane = tid & 63;
    const int grp = bid >> 6;          // bm (phase1) == bw (phase3)
    const int sub = bid & 63;          // nt (phase1) == mt (phase3)
    const int b = grp >> 1, which = grp & 1;
    const int col = lane & 15, g = lane >> 4;

    // ===================== phase 1: prep ====================================
    {
        const int mod = which;
        const float* wv = mod ? wv_ir : wv_vi;
        const float* bv = mod ? bv_ir : bv_vi;
        const float* x = (mod ? ir : vi) + b * (64 * 4096);
        // stage W (64x64 bf16, row-XOR-swizzled) into vbuf[0]
        if (tid < 256) {
            const float* src = wv + tid * 16;
            int row = tid >> 2, colb = (tid & 3) * 32;
            int pk[8];
            #pragma unroll
            for (int j = 0; j < 8; ++j)
                asm("v_cvt_pk_bf16_f32 %0, %1, %2" : "=v"(pk[j])
                    : "v"(src[2 * j]), "v"(src[2 * j + 1]));
            int sw = (row & 7) << 4;
            i32x4 lo = {pk[0], pk[1], pk[2], pk[3]};
            i32x4 hi = {pk[4], pk[5], pk[6], pk[7]};
            *(i32x4*)(vbuf[0] + row * 128 + (colb ^ sw)) = lo;
            *(i32x4*)(vbuf[0] + row * 128 + ((colb + 16) ^ sw)) = hi;
        }
        __syncthreads();
        if (wvw < 4) {
            // value GEMM: V[c,n] = W[c,:] x[:,n] + b; s[n] byproduct
            const int n = sub * 64 + wvw * 16 + col;
            bf16x8 afr[4][2];
            #pragma unroll
            for (int cb = 0; cb < 4; ++cb) {
                int row = cb * 16 + col;
                int sw = (row & 7) << 4;
                #pragma unroll
                for (int ks = 0; ks < 2; ++ks)
                    afr[cb][ks] = *(const bf16x8*)(vbuf[0] + row * 128 + ((ks * 64 + g * 16) ^ sw));
            }
            float ssum = 0.f;
            bf16x8 bfr[2];
            #pragma unroll
            for (int ks = 0; ks < 2; ++ks) {
                const float* xr = x + (ks * 32 + g * 8) * 4096 + n;
                float v[8];
                #pragma unroll
                for (int j = 0; j < 8; ++j) { v[j] = xr[j * 4096]; ssum += v[j]; }
                int pk[4];
                #pragma unroll
                for (int j = 0; j < 4; ++j)
                    asm("v_cvt_pk_bf16_f32 %0, %1, %2" : "=v"(pk[j])
                        : "v"(v[2 * j]), "v"(v[2 * j + 1]));
                i32x4 bi = {pk[0], pk[1], pk[2], pk[3]};
                bfr[ks] = __builtin_bit_cast(bf16x8, bi);
            }
            ssum += __shfl_xor(ssum, 16);
            ssum += __shfl_xor(ssum, 32);
            if (lane < 16) s[grp * 4096 + sub * 64 + wvw * 16 + lane] = ssum;

            f32x4 acc[4];
            #pragma unroll
            for (int cb = 0; cb < 4; ++cb)
                #pragma unroll
                for (int r = 0; r < 4; ++r) acc[cb][r] = bv[cb * 16 + g * 4 + r];
            #pragma unroll
            for (int ks = 0; ks < 2; ++ks)
                #pragma unroll
                for (int cb = 0; cb < 4; ++cb)
                    acc[cb] = __builtin_amdgcn_mfma_f32_16x16x32_bf16(afr[cb][ks], bfr[ks], acc[cb], 0, 0, 0);
            __hip_bfloat16* outp = Vc + (size_t)(grp * 64) * 4096 + n;
            #pragma unroll
            for (int cb = 0; cb < 4; ++cb)
                #pragma unroll
                for (int r = 0; r < 4; ++r)
                    outp[(cb * 16 + g * 4 + r) * 4096] = __float2bfloat16(acc[cb][r]);
        } else if (wvw == 4) {
            // Ad[d] = sum_c w1_q[d, :]
            int d = lane >> 3, i = lane & 7;
            const float* p = w1_q + d * 128 + i * 16;
            float v = 0.f;
            #pragma unroll
            for (int k = 0; k < 16; ++k) v += p[k];
            #pragma unroll
            for (int o = 1; o < 8; o <<= 1) v += __shfl_xor(v, o);
            if (i == 0) agA[d] = v;
        } else if (wvw == 5) {
            // Cx[d] = sum_c w1_key[d, :]  (key weights of this block's attn)
            const float* w1x = which ? w1_vi : w1_ir;
            int d = lane >> 3, i = lane & 7;
            const float* p = w1x + d * 64 + i * 8;
            float v = 0.f;
            #pragma unroll
            for (int k = 0; k < 8; ++k) v += p[k];
            #pragma unroll
            for (int o = 1; o < 8; o <<= 1) v += __shfl_xor(v, o);
            if (i == 0) agC[d] = v;
        } else if (wvw == 6) {
            if (lane < 8) agB[lane] = b1_q[lane];
        }
        __syncthreads();
    }
    float alpha = 0.f, gamma = 0.f;
    #pragma unroll
    for (int d = 0; d < 8; ++d) {
        alpha = fmaf(agA[d], agC[d], alpha);
        gamma = fmaf(agB[d], agC[d], gamma);
    }

    cg::this_grid().sync();

    // ===================== phase 3: attention ===============================
    const int amod = which ? 0 : 1;
    const float* wsxa = amod ? wsx_ir : wsx_vi;
    const float* wsya = amod ? wsy_ir : wsy_vi;
    const short* Vg = (const short*)(Vc + (size_t)(grp * 64) * 4096);
    const int h = wvw >> 2, wvt = wvw & 3;
    const int m = sub * 64 + wvt * 16 + col;

    // stage s[b][2][4096] into vbuf[0]
    float* sld = (float*)vbuf[0];
    const float* sg = s + (size_t)(b * 2) * 4096;
    #pragma unroll
    for (int k = 0; k < 16; ++k) { int i = tid + k * 512; sld[i] = sg[i]; }
    __syncthreads();

    // e_att field + block-local min/max (identical across blocks); e_q at m
    float mn = 3.0e38f, mx = 0.f;
    {
        const float* sa = sld + amod * 4096;
        #pragma unroll
        for (int k2 = 0; k2 < 8; ++k2) {
            int n = tid + k2 * 512;
            int hh = n >> 6, ww = n & 63;
            float gx = 0.f, gy = 0.f;
            #pragma unroll
            for (int di = 0; di < 3; ++di)
                #pragma unroll
                for (int dj = 0; dj < 3; ++dj) {
                    int r = hh + di - 1, c2 = ww + dj - 1;
                    bool in = (r >= 0) & (r < 64) & (c2 >= 0) & (c2 < 64);
                    float v = in ? sa[r * 64 + c2] : 0.f;
                    int kk = di * 3 + dj;
                    gx = fmaf(v, wsxa[kk], gx);
                    gy = fmaf(v, wsya[kk], gy);
                }
            float ev = fabsf(gx) + fabsf(gy);
            elds[n] = ev;
            mn = fminf(mn, ev); mx = fmaxf(mx, ev);
        }
    }
    float eq;
    {
        int ww = wvt * 16 + col;
        float gx = 0.f, gy = 0.f;
        #pragma unroll
        for (int di = 0; di < 3; ++di)
            #pragma unroll
            for (int dj = 0; dj < 3; ++dj) {
                int r = sub + di - 1, c2 = ww + dj - 1;
                bool in = (r >= 0) & (r < 64) & (c2 >= 0) & (c2 < 64);
                float v = in ? (sld[r * 64 + c2] + sld[4096 + r * 64 + c2]) : 0.f;
                int kk = di * 3 + dj;
                gx = fmaf(v, wsx_q[kk], gx);
                gy = fmaf(v, wsy_q[kk], gy);
            }
        eq = fabsf(gx) + fabsf(gy);
    }
    #pragma unroll
    for (int o = 32; o; o >>= 1) {
        mn = fminf(mn, __shfl_xor(mn, o));
        mx = fmaxf(mx, __shfl_xor(mx, o));
    }
    if (lane == 0) { mm[wvw] = mn; mm[8 + wvw] = mx; }
    __syncthreads();
    float emn = mm[0], emx = mm[8];
    #pragma unroll
    for (int w = 1; w < 8; ++w) {
        emn = fminf(emn, mm[w]); emx = fmaxf(emx, mm[8 + w]);
    }
    const float L2E = 1.4426950408889634f;
    const float t  = alpha * eq + gamma;
    const float t2 = t * L2E;
    const float nM2 = -((t > 0.f) ? t * emx : t * emn) * L2E;

    // stage V chunk 0 (overwrites sld)
    #pragma unroll
    for (int k = 0; k < 8; ++k) {
        int id = tid + k * 512;
        int c = id >> 6, ss = id & 63;
        bf16x8 v = *(const bf16x8*)(Vg + c * 4096 + ss * 8);
        *(bf16x8*)(vbuf[0] + c * 1024 + ((ss * 16) ^ ((c & 31) << 4))) = v;
    }
    __syncthreads();

    f32x4 acc[4] = {};
    f32x4 accz = {};
    bf16x8 ones;
    #pragma unroll
    for (int j = 0; j < 8; ++j) ones[j] = (short)0x3F80;

    for (int ck = 0; ck < NCH; ++ck) {
        bf16x8 stg[8];
        const bool pf = (ck + 1 < NCH);
        if (pf) {
            const short* src = Vg + (ck + 1) * CH;
            #pragma unroll
            for (int k = 0; k < 8; ++k) {
                int id = tid + k * 512;
                int c = id >> 6, ss = id & 63;
                stg[k] = *(const bf16x8*)(src + c * 4096 + ss * 8);
            }
        }
        const char* vb = vbuf[ck & 1];
        const float* el = elds + ck * CH;
        #pragma unroll
        for (int it2 = 0; it2 < 8; ++it2) {
            const int n0 = (h * 8 + it2) * 32;
            bf16x8 af[4];
            #pragma unroll
            for (int cb = 0; cb < 4; ++cb) {
                int row = cb * 16 + col;
                int byte = row * 1024 + (((n0 + g * 8) * 2) ^ ((row & 31) << 4));
                af[cb] = *(const bf16x8*)(vb + byte);
            }
            f32x4 e0 = *(const f32x4*)(el + n0 + g * 8);
            f32x4 e1 = *(const f32x4*)(el + n0 + g * 8 + 4);
            float p[8];
            #pragma unroll
            for (int j = 0; j < 4; ++j) {
                float g0 = fmaf(e0[j], t2, nM2);
                float g1 = fmaf(e1[j], t2, nM2);
                asm("v_exp_f32 %0, %1" : "=v"(p[j])     : "v"(g0));
                asm("v_exp_f32 %0, %1" : "=v"(p[j + 4]) : "v"(g1));
            }
            int pk0, pk1, pk2, pk3;
            asm("v_cvt_pk_bf16_f32 %0, %1, %2" : "=v"(pk0) : "v"(p[0]), "v"(p[1]));
            asm("v_cvt_pk_bf16_f32 %0, %1, %2" : "=v"(pk1) : "v"(p[2]), "v"(p[3]));
            asm("v_cvt_pk_bf16_f32 %0, %1, %2" : "=v"(pk2) : "v"(p[4]), "v"(p[5]));
            asm("v_cvt_pk_bf16_f32 %0, %1, %2" : "=v"(pk3) : "v"(p[6]), "v"(p[7]));
            i32x4 pki = {pk0, pk1, pk2, pk3};
            bf16x8 bfrag = __builtin_bit_cast(bf16x8, pki);
            #pragma unroll
            for (int cb = 0; cb < 4; ++cb)
                acc[cb] = __builtin_amdgcn_mfma_f32_16x16x32_bf16(af[cb], bfrag, acc[cb], 0, 0, 0);
            accz = __builtin_amdgcn_mfma_f32_16x16x32_bf16(ones, bfrag, accz, 0, 0, 0);
        }
        __syncthreads();
        if (pf) {
            char* wb = vbuf[(ck + 1) & 1];
            #pragma unroll
            for (int k = 0; k < 8; ++k) {
                int id = tid + k * 512;
                int c = id >> 6, ss = id & 63;
                *(bf16x8*)(wb + c * 1024 + ((ss * 16) ^ ((c & 31) << 4))) = stg[k];
            }
            __syncthreads();
        }
    }

    // combine chunk-halves via LDS, normalize, write final output
    float* red = (float*)vbuf[0];
    if (h == 1) {
        int base = (wvt * 64 + lane) * 21;
        #pragma unroll
        for (int cb = 0; cb < 4; ++cb)
            *(f32x4*)(red + base + cb * 4) = acc[cb];
        red[base + 16] = accz[0];
    }
    __syncthreads();
    if (h == 0) {
        int base = (wvt * 64 + lane) * 21;
        #pragma unroll
        for (int cb = 0; cb < 4; ++cb)
            acc[cb] += *(const f32x4*)(red + base + cb * 4);
        float z = accz[0] + red[base + 16];
        float inv = 1.0f / z;
        float* ob = out + which * (2 * 64 * 4096) + b * (64 * 4096) + m;
        #pragma unroll
        for (int cb = 0; cb < 4; ++cb) {
            int c = cb * 16 + g * 4;
            #pragma unroll
            for (int r = 0; r < 4; ++r) ob[(c + r) * 4096] = acc[cb][r] * inv;
        }
    }
}

extern "C" void kernel_launch(void* const* d_in, const int* in_sizes, int n_in,
                              void* d_out, int out_size, void* d_ws, size_t ws_size,
                              hipStream_t stream) {
    const float* vi     = (const float*)d_in[0];
    const float* ir     = (const float*)d_in[1];
    const float* wsx_vi = (const float*)d_in[2];
    const float* wsy_vi = (const float*)d_in[3];
    const float* w1_vi  = (const float*)d_in[4];
    const float* wsx_q  = (const float*)d_in[6];
    const float* wsy_q  = (const float*)d_in[7];
    const float* w1_q   = (const float*)d_in[8];
    const float* b1_q   = (const float*)d_in[9];
    const float* wsx_ir = (const float*)d_in[10];
    const float* wsy_ir = (const float*)d_in[11];
    const float* w1_ir  = (const float*)d_in[12];
    const float* wv_vi  = (const float*)d_in[14];
    const float* bv_vi  = (const float*)d_in[15];
    const float* wv_ir  = (const float*)d_in[16];
    const float* bv_ir  = (const float*)d_in[17];
    (void)in_sizes; (void)n_in; (void)out_size;

    char* ws = (char*)d_ws;
    float* s = (float*)ws;                                  // 64 KB [4][4096]
    __hip_bfloat16* Vc = (__hip_bfloat16*)(ws + 65536);     // 2 MB
    float* out = (float*)d_out;
    (void)ws_size;

    void* args[] = { (void*)&vi, (void*)&ir,
                     (void*)&wsx_vi, (void*)&wsy_vi, (void*)&wsx_q, (void*)&wsy_q,
                     (void*)&wsx_ir, (void*)&wsy_ir,
                     (void*)&w1_vi, (void*)&w1_q, (void*)&b1_q, (void*)&w1_ir,
                     (void*)&wv_vi, (void*)&bv_vi, (void*)&wv_ir, (void*)&bv_ir,
                     (void*)&s, (void*)&Vc, (void*)&out };
    hipLaunchCooperativeKernel((void*)kAll, dim3(256), dim3(512), args, 0, stream);
}

// Round 12
// 37.665 us; speedup vs baseline: 1.7927x; 1.7927x over previous
//
#include <hip/hip_runtime.h>
#include <hip/hip_bf16.h>

typedef __attribute__((ext_vector_type(8))) short bf16x8;
typedef __attribute__((ext_vector_type(8))) __bf16 bf16v8;
typedef __attribute__((ext_vector_type(4))) float f32x4;
typedef __attribute__((ext_vector_type(4))) int   i32x4;

#if __has_builtin(__builtin_amdgcn_exp2f)
#define EXP2(x) __builtin_amdgcn_exp2f(x)
#else
#define EXP2(x) exp2f(x)
#endif

// ---------------------------------------------------------------------------
// B=2, C=64, H=W=64, N=4096, dk=8.
// Sobel weights broadcast over [C,C,3,3] -> conv = conv(chansum). Keys/queries
// affine in scalar field e[n]; attn row m = softmax_n(t_m*e[n]),
// t_m = alpha*eq[m]+gamma; row max = t*e_max (t>0) else t*e_min.
// 2 graph nodes: kP (value GEMM + s byproduct + alpha/gamma) ->
//                k4 (per-block sobel recompute + full-K attention).
// R6/R10: __threadfence combine AND grid.sync() cost ~2x the pipeline on
// gfx950 (cross-XCD coherence). Only kernel-boundary sync.
// R11 lesson (NaN): long runs of inline-asm v_exp/v_cvt are NOT covered by
// the compiler's hazard recognizer; a reschedule exposed a stale-register
// hazard. Fix: builtin exp2 + native __bf16 casts (compiler-modeled; also
// faster per m240). MT=4 m-groups per wave -> V fragments read once per n0
// (block LDS read traffic 3MB -> 768KB).
// ---------------------------------------------------------------------------

// kP: blocks 0..255 value GEMM (V[c,n] = W x + b) + s byproduct;
//     block 256: alpha/gamma reduction.
__global__ __launch_bounds__(256) void kP_prep(
    const float* __restrict__ vi, const float* __restrict__ ir,
    const float* __restrict__ w1_vi, const float* __restrict__ w1_q,
    const float* __restrict__ b1_q,  const float* __restrict__ w1_ir,
    const float* __restrict__ wv_vi, const float* __restrict__ bv_vi,
    const float* __restrict__ wv_ir, const float* __restrict__ bv_ir,
    float* __restrict__ s, float* __restrict__ scal,
    __hip_bfloat16* __restrict__ Vc) {
    const int t = threadIdx.x;
    if (blockIdx.x < 256) {
        __shared__ __align__(16) char wlds[64 * 128];   // 64x64 bf16 swizzled
        const int bm = blockIdx.x >> 6, nt = blockIdx.x & 63;
        const int b = bm >> 1, mod = bm & 1;
        const float* wv = mod ? wv_ir : wv_vi;
        const float* bv = mod ? bv_ir : bv_vi;
        const float* x = (mod ? ir : vi) + b * (64 * 4096);
        {
            const float* src = wv + t * 16;
            int row = t >> 2, colb = (t & 3) * 32;
            bf16v8 lo8, hi8;
            #pragma unroll
            for (int j = 0; j < 8; ++j) {
                lo8[j] = (__bf16)src[j];
                hi8[j] = (__bf16)src[8 + j];
            }
            int sw = (row & 7) << 4;
            *(i32x4*)(wlds + row * 128 + (colb ^ sw)) = __builtin_bit_cast(i32x4, lo8);
            *(i32x4*)(wlds + row * 128 + ((colb + 16) ^ sw)) = __builtin_bit_cast(i32x4, hi8);
        }
        __syncthreads();
        const int wvid = t >> 6, lane = t & 63;
        const int col = lane & 15, g = lane >> 4;
        const int n = nt * 64 + wvid * 16 + col;
        bf16x8 afr[4][2];
        #pragma unroll
        for (int cb = 0; cb < 4; ++cb) {
            int row = cb * 16 + col;
            int sw = (row & 7) << 4;
            #pragma unroll
            for (int ks = 0; ks < 2; ++ks)
                afr[cb][ks] = *(const bf16x8*)(wlds + row * 128 + ((ks * 64 + g * 16) ^ sw));
        }
        float ssum = 0.f;
        bf16x8 bfr[2];
        #pragma unroll
        for (int ks = 0; ks < 2; ++ks) {
            const float* xr = x + (ks * 32 + g * 8) * 4096 + n;
            bf16v8 pb;
            #pragma unroll
            for (int j = 0; j < 8; ++j) {
                float v = xr[j * 4096];
                ssum += v;
                pb[j] = (__bf16)v;
            }
            bfr[ks] = __builtin_bit_cast(bf16x8, pb);
        }
        ssum += __shfl_xor(ssum, 16);
        ssum += __shfl_xor(ssum, 32);
        if (lane < 16) s[bm * 4096 + nt * 64 + wvid * 16 + lane] = ssum;

        f32x4 acc[4];
        #pragma unroll
        for (int cb = 0; cb < 4; ++cb)
            #pragma unroll
            for (int r = 0; r < 4; ++r) acc[cb][r] = bv[cb * 16 + g * 4 + r];
        #pragma unroll
        for (int ks = 0; ks < 2; ++ks)
            #pragma unroll
            for (int cb = 0; cb < 4; ++cb)
                acc[cb] = __builtin_amdgcn_mfma_f32_16x16x32_bf16(afr[cb][ks], bfr[ks], acc[cb], 0, 0, 0);
        __hip_bfloat16* outp = Vc + (size_t)(bm * 64) * 4096 + n;
        #pragma unroll
        for (int cb = 0; cb < 4; ++cb)
            #pragma unroll
            for (int r = 0; r < 4; ++r)
                outp[(cb * 16 + g * 4 + r) * 4096] = __float2bfloat16(acc[cb][r]);
    } else {
        __shared__ float Ad[8], Cv[8], Ci[8], Bq[8];
        if (t < 8) {
            float a = 0.f;
            for (int c = 0; c < 128; ++c) a += w1_q[t * 128 + c];
            float cv = 0.f, ci = 0.f;
            for (int c = 0; c < 64; ++c) { cv += w1_vi[t * 64 + c]; ci += w1_ir[t * 64 + c]; }
            Ad[t] = a; Cv[t] = cv; Ci[t] = ci; Bq[t] = b1_q[t];
        }
        __syncthreads();
        if (t == 0) {
            float av = 0, gv = 0, ai = 0, gi = 0;
            for (int d = 0; d < 8; ++d) {
                av += Ad[d] * Cv[d]; gv += Bq[d] * Cv[d];
                ai += Ad[d] * Ci[d]; gi += Bq[d] * Ci[d];
            }
            scal[0] = av; scal[1] = gv; scal[2] = ai; scal[3] = gi;
        }
    }
}

// k4: per block: stage s, sobel-recompute e_att -> elds + min/max, 4 eq/lane.
// Main loop: 8 chunks of 512; the 16 n0-segments split across 8 waves (2
// each); each wave carries MT=4 m-groups in-register so each V fragment is
// read from LDS exactly once per (wave, n0).
// Epilogue: 8-way partial reduce via padded LDS, output split (mg, c-half).
#define CH 512
#define NCH 8
__global__ __launch_bounds__(512, 2) void k4_attn(
        const float* __restrict__ s, const float* __restrict__ scal,
        const float* __restrict__ wsx_vi, const float* __restrict__ wsy_vi,
        const float* __restrict__ wsx_q,  const float* __restrict__ wsy_q,
        const float* __restrict__ wsx_ir, const float* __restrict__ wsy_ir,
        const __hip_bfloat16* __restrict__ Vc, float* __restrict__ out) {
    __shared__ __align__(16) char smem[147456];   // vbuf[2][64KB] + elds 16KB
    __shared__ float mm[16];
    char* vbuf0 = smem;
    char* vbuf1 = smem + 65536;
    float* elds = (float*)(smem + 131072);        // e_att[4096]
    const int mt = blockIdx.x;    // spatial row (64 m-rows per block)
    const int bw = blockIdx.y;    // b*2+which
    const int b = bw >> 1, which = bw & 1;
    const int amod = which ? 0 : 1;
    const float* wsxa = amod ? wsx_ir : wsx_vi;
    const float* wsya = amod ? wsy_ir : wsy_vi;
    const float alpha = scal[which ? 0 : 2];
    const float gamma = scal[which ? 1 : 3];
    const short* Vg = (const short*)(Vc + (size_t)(bw * 64) * 4096);

    const int tid = threadIdx.x;
    const int wvw = tid >> 6, lane = tid & 63;
    const int col = lane & 15, g = lane >> 4;

    // ---- phase A: stage s[b][2][4096] into vbuf0 --------------------------
    float* sld = (float*)vbuf0;
    const float* sg = s + (size_t)(b * 2) * 4096;
    #pragma unroll
    for (int k = 0; k < 16; ++k) { int i = tid + k * 512; sld[i] = sg[i]; }
    __syncthreads();

    // ---- phase B: e_att field + min/max; eq per m-group -------------------
    float mn = 3.0e38f, mx = 0.f;
    {
        const float* sa = sld + amod * 4096;
        #pragma unroll
        for (int k2 = 0; k2 < 8; ++k2) {
            int n = tid + k2 * 512;
            int hh = n >> 6, ww = n & 63;
            float gx = 0.f, gy = 0.f;
            #pragma unroll
            for (int di = 0; di < 3; ++di)
                #pragma unroll
                for (int dj = 0; dj < 3; ++dj) {
                    int r = hh + di - 1, c2 = ww + dj - 1;
                    bool in = (r >= 0) & (r < 64) & (c2 >= 0) & (c2 < 64);
                    float v = in ? sa[r * 64 + c2] : 0.f;
                    int kk = di * 3 + dj;
                    gx = fmaf(v, wsxa[kk], gx);
                    gy = fmaf(v, wsya[kk], gy);
                }
            float ev = fabsf(gx) + fabsf(gy);
            elds[n] = ev;
            mn = fminf(mn, ev); mx = fmaxf(mx, ev);
        }
    }
    float eq[4];
    #pragma unroll
    for (int mg = 0; mg < 4; ++mg) {
        int ww = mg * 16 + col;
        float gx = 0.f, gy = 0.f;
        #pragma unroll
        for (int di = 0; di < 3; ++di)
            #pragma unroll
            for (int dj = 0; dj < 3; ++dj) {
                int r = mt + di - 1, c2 = ww + dj - 1;
                bool in = (r >= 0) & (r < 64) & (c2 >= 0) & (c2 < 64);
                float v = in ? (sld[r * 64 + c2] + sld[4096 + r * 64 + c2]) : 0.f;
                int kk = di * 3 + dj;
                gx = fmaf(v, wsx_q[kk], gx);
                gy = fmaf(v, wsy_q[kk], gy);
            }
        eq[mg] = fabsf(gx) + fabsf(gy);
    }
    #pragma unroll
    for (int o = 32; o; o >>= 1) {
        mn = fminf(mn, __shfl_xor(mn, o));
        mx = fmaxf(mx, __shfl_xor(mx, o));
    }
    if (lane == 0) { mm[wvw] = mn; mm[8 + wvw] = mx; }
    __syncthreads();             // closes sld reads too
    float emn = mm[0], emx = mm[8];
    #pragma unroll
    for (int w = 1; w < 8; ++w) {
        emn = fminf(emn, mm[w]); emx = fmaxf(emx, mm[8 + w]);
    }
    const float L2E = 1.4426950408889634f;
    float t2[4], nM2[4];
    #pragma unroll
    for (int mg = 0; mg < 4; ++mg) {
        float t = alpha * eq[mg] + gamma;
        t2[mg]  = t * L2E;
        nM2[mg] = -((t > 0.f) ? t * emx : t * emn) * L2E;
    }

    // ---- phase C: stage V chunk 0 (overwrites sld) ------------------------
    #pragma unroll
    for (int k = 0; k < 8; ++k) {
        int id = tid + k * 512;
        int c = id >> 6, ss = id & 63;
        bf16x8 v = *(const bf16x8*)(Vg + c * 4096 + ss * 8);
        *(bf16x8*)(vbuf0 + c * 1024 + ((ss * 16) ^ ((c & 31) << 4))) = v;
    }
    __syncthreads();

    f32x4 acc[4][4] = {};
    f32x4 accz[4] = {};
    bf16x8 ones;
    #pragma unroll
    for (int j = 0; j < 8; ++j) ones[j] = (short)0x3F80;

    for (int ck = 0; ck < NCH; ++ck) {
        bf16x8 stg[8];
        const bool pf = (ck + 1 < NCH);
        if (pf) {
            const short* src = Vg + (ck + 1) * CH;
            #pragma unroll
            for (int k = 0; k < 8; ++k) {
                int id = tid + k * 512;
                int c = id >> 6, ss = id & 63;
                stg[k] = *(const bf16x8*)(src + c * 4096 + ss * 8);
            }
        }
        const char* vb = (ck & 1) ? vbuf1 : vbuf0;
        const float* el = elds + ck * CH;
        #pragma unroll
        for (int j = 0; j < 2; ++j) {
            const int n0 = (wvw * 2 + j) * 32;
            bf16x8 af[4];
            #pragma unroll
            for (int cb = 0; cb < 4; ++cb) {
                int row = cb * 16 + col;
                int byte = row * 1024 + (((n0 + g * 8) * 2) ^ ((row & 31) << 4));
                af[cb] = *(const bf16x8*)(vb + byte);
            }
            f32x4 e0 = *(const f32x4*)(el + n0 + g * 8);
            f32x4 e1 = *(const f32x4*)(el + n0 + g * 8 + 4);
            #pragma unroll
            for (int mg = 0; mg < 4; ++mg) {
                bf16v8 pb;
                #pragma unroll
                for (int q = 0; q < 4; ++q) {
                    float g0 = fmaf(e0[q], t2[mg], nM2[mg]);
                    float g1 = fmaf(e1[q], t2[mg], nM2[mg]);
                    pb[q]     = (__bf16)EXP2(g0);
                    pb[q + 4] = (__bf16)EXP2(g1);
                }
                bf16x8 bfrag = __builtin_bit_cast(bf16x8, pb);
                #pragma unroll
                for (int cb = 0; cb < 4; ++cb)
                    acc[mg][cb] = __builtin_amdgcn_mfma_f32_16x16x32_bf16(af[cb], bfrag, acc[mg][cb], 0, 0, 0);
                accz[mg] = __builtin_amdgcn_mfma_f32_16x16x32_bf16(ones, bfrag, accz[mg], 0, 0, 0);
            }
        }
        __syncthreads();
        if (pf) {
            char* wb = (ck & 1) ? vbuf0 : vbuf1;
            #pragma unroll
            for (int k = 0; k < 8; ++k) {
                int id = tid + k * 512;
                int c = id >> 6, ss = id & 63;
                *(bf16x8*)(wb + c * 1024 + ((ss * 16) ^ ((c & 31) << 4))) = stg[k];
            }
            __syncthreads();
        }
    }

    // ---- epilogue: 8-way reduce via LDS (stride 17 floats, bank-safe) -----
    float* rbuf = (float*)smem;   // [src8][mg4][lane64][17] = 139264 B
    #pragma unroll
    for (int mg = 0; mg < 4; ++mg) {
        int base = ((wvw * 4 + mg) * 64 + lane) * 17;
        #pragma unroll
        for (int cb = 0; cb < 4; ++cb)
            *(f32x4*)(rbuf + base + cb * 4) = acc[mg][cb];
        rbuf[base + 16] = accz[mg][0];
    }
    __syncthreads();
    {
        const int mg = wvw & 3, hh = wvw >> 2;
        f32x4 sum0 = {}, sum1 = {};
        float z = 0.f;
        #pragma unroll
        for (int src = 0; src < 8; ++src) {
            int sb = ((src * 4 + mg) * 64 + lane) * 17;
            sum0 += *(const f32x4*)(rbuf + sb + (hh * 2 + 0) * 4);
            sum1 += *(const f32x4*)(rbuf + sb + (hh * 2 + 1) * 4);
            z += rbuf[sb + 16];
        }
        float inv = 1.0f / z;
        int m = mt * 64 + mg * 16 + col;
        float* ob = out + which * (2 * 64 * 4096) + b * (64 * 4096) + m;
        int c0 = (hh * 2) * 16 + g * 4;
        int c1 = (hh * 2 + 1) * 16 + g * 4;
        #pragma unroll
        for (int r = 0; r < 4; ++r) ob[(c0 + r) * 4096] = sum0[r] * inv;
        #pragma unroll
        for (int r = 0; r < 4; ++r) ob[(c1 + r) * 4096] = sum1[r] * inv;
    }
}

extern "C" void kernel_launch(void* const* d_in, const int* in_sizes, int n_in,
                              void* d_out, int out_size, void* d_ws, size_t ws_size,
                              hipStream_t stream) {
    const float* vi     = (const float*)d_in[0];
    const float* ir     = (const float*)d_in[1];
    const float* wsx_vi = (const float*)d_in[2];
    const float* wsy_vi = (const float*)d_in[3];
    const float* w1_vi  = (const float*)d_in[4];
    const float* wsx_q  = (const float*)d_in[6];
    const float* wsy_q  = (const float*)d_in[7];
    const float* w1_q   = (const float*)d_in[8];
    const float* b1_q   = (const float*)d_in[9];
    const float* wsx_ir = (const float*)d_in[10];
    const float* wsy_ir = (const float*)d_in[11];
    const float* w1_ir  = (const float*)d_in[12];
    const float* wv_vi  = (const float*)d_in[14];
    const float* bv_vi  = (const float*)d_in[15];
    const float* wv_ir  = (const float*)d_in[16];
    const float* bv_ir  = (const float*)d_in[17];
    (void)in_sizes; (void)n_in; (void)out_size;

    char* ws = (char*)d_ws;
    float* scal = (float*)ws;                              // 64 B used
    float* s    = (float*)(ws + 1280);                     // 64 KB [4][4096]
    __hip_bfloat16* Vc = (__hip_bfloat16*)(ws + 1280 + 65536);  // 2 MB
    float* out = (float*)d_out;
    (void)ws_size;

    kP_prep<<<dim3(257), 256, 0, stream>>>(vi, ir, w1_vi, w1_q, b1_q, w1_ir,
                                           wv_vi, bv_vi, wv_ir, bv_ir, s, scal, Vc);
    k4_attn<<<dim3(64, 4), 512, 0, stream>>>(s, scal, wsx_vi, wsy_vi, wsx_q, wsy_q,
                                             wsx_ir, wsy_ir, Vc, out);
}

// Round 13
// 32.406 us; speedup vs baseline: 2.0836x; 1.1623x over previous
//
#include <hip/hip_runtime.h>
#include <hip/hip_bf16.h>

typedef __attribute__((ext_vector_type(8))) short bf16x8;
typedef __attribute__((ext_vector_type(8))) __bf16 bf16v8;
typedef __attribute__((ext_vector_type(4))) float f32x4;
typedef __attribute__((ext_vector_type(4))) int   i32x4;

#if __has_builtin(__builtin_amdgcn_exp2f)
#define EXP2(x) __builtin_amdgcn_exp2f(x)
#else
#define EXP2(x) exp2f(x)
#endif

// ---------------------------------------------------------------------------
// B=2, C=64, H=W=64, N=4096, dk=8.
// Sobel weights broadcast over [C,C,3,3] -> conv = conv(chansum). Keys/queries
// affine in scalar field e[n]; attn row m = softmax_n(t_m*e[n]),
// t_m = alpha*eq[m]+gamma; row max = t*e_max (t>0) else t*e_min.
// 2 graph nodes: kP (value GEMM + s byproduct + alpha/gamma) ->
//                k4 (per-block sobel recompute + full-K attention).
// R6/R10: __threadfence combine AND grid.sync() cost ~2x the pipeline on
// gfx950 (cross-XCD coherence). Only kernel-boundary sync.
// R11: inline-asm exp/cvt runs dodge the compiler hazard recognizer -> NaN;
// use builtin exp2 + native __bf16 casts (also faster, m240).
// R12: MT-4-per-wave (fewer, longer wave tasks) regressed -> keep R9's
// one-m-tile-per-wave shape; independent per-wave iters beat LDS-read savings.
// R13: 16 waves/block (4/SIMD) — R7 proved wave-count doubling is the lever.
// ---------------------------------------------------------------------------

// kP: blocks 0..255 value GEMM (V[c,n] = W x + b) + s byproduct;
//     block 256: alpha/gamma reduction.
__global__ __launch_bounds__(256) void kP_prep(
    const float* __restrict__ vi, const float* __restrict__ ir,
    const float* __restrict__ w1_vi, const float* __restrict__ w1_q,
    const float* __restrict__ b1_q,  const float* __restrict__ w1_ir,
    const float* __restrict__ wv_vi, const float* __restrict__ bv_vi,
    const float* __restrict__ wv_ir, const float* __restrict__ bv_ir,
    float* __restrict__ s, float* __restrict__ scal,
    __hip_bfloat16* __restrict__ Vc) {
    const int t = threadIdx.x;
    if (blockIdx.x < 256) {
        __shared__ __align__(16) char wlds[64 * 128];   // 64x64 bf16 swizzled
        const int bm = blockIdx.x >> 6, nt = blockIdx.x & 63;
        const int b = bm >> 1, mod = bm & 1;
        const float* wv = mod ? wv_ir : wv_vi;
        const float* bv = mod ? bv_ir : bv_vi;
        const float* x = (mod ? ir : vi) + b * (64 * 4096);
        {
            const float* src = wv + t * 16;
            int row = t >> 2, colb = (t & 3) * 32;
            bf16v8 lo8, hi8;
            #pragma unroll
            for (int j = 0; j < 8; ++j) {
                lo8[j] = (__bf16)src[j];
                hi8[j] = (__bf16)src[8 + j];
            }
            int sw = (row & 7) << 4;
            *(i32x4*)(wlds + row * 128 + (colb ^ sw)) = __builtin_bit_cast(i32x4, lo8);
            *(i32x4*)(wlds + row * 128 + ((colb + 16) ^ sw)) = __builtin_bit_cast(i32x4, hi8);
        }
        __syncthreads();
        const int wvid = t >> 6, lane = t & 63;
        const int col = lane & 15, g = lane >> 4;
        const int n = nt * 64 + wvid * 16 + col;
        bf16x8 afr[4][2];
        #pragma unroll
        for (int cb = 0; cb < 4; ++cb) {
            int row = cb * 16 + col;
            int sw = (row & 7) << 4;
            #pragma unroll
            for (int ks = 0; ks < 2; ++ks)
                afr[cb][ks] = *(const bf16x8*)(wlds + row * 128 + ((ks * 64 + g * 16) ^ sw));
        }
        float ssum = 0.f;
        bf16x8 bfr[2];
        #pragma unroll
        for (int ks = 0; ks < 2; ++ks) {
            const float* xr = x + (ks * 32 + g * 8) * 4096 + n;
            bf16v8 pb;
            #pragma unroll
            for (int j = 0; j < 8; ++j) {
                float v = xr[j * 4096];
                ssum += v;
                pb[j] = (__bf16)v;
            }
            bfr[ks] = __builtin_bit_cast(bf16x8, pb);
        }
        ssum += __shfl_xor(ssum, 16);
        ssum += __shfl_xor(ssum, 32);
        if (lane < 16) s[bm * 4096 + nt * 64 + wvid * 16 + lane] = ssum;

        f32x4 acc[4];
        #pragma unroll
        for (int cb = 0; cb < 4; ++cb)
            #pragma unroll
            for (int r = 0; r < 4; ++r) acc[cb][r] = bv[cb * 16 + g * 4 + r];
        #pragma unroll
        for (int ks = 0; ks < 2; ++ks)
            #pragma unroll
            for (int cb = 0; cb < 4; ++cb)
                acc[cb] = __builtin_amdgcn_mfma_f32_16x16x32_bf16(afr[cb][ks], bfr[ks], acc[cb], 0, 0, 0);
        __hip_bfloat16* outp = Vc + (size_t)(bm * 64) * 4096 + n;
        #pragma unroll
        for (int cb = 0; cb < 4; ++cb)
            #pragma unroll
            for (int r = 0; r < 4; ++r)
                outp[(cb * 16 + g * 4 + r) * 4096] = __float2bfloat16(acc[cb][r]);
    } else {
        __shared__ float Ad[8], Cv[8], Ci[8], Bq[8];
        if (t < 8) {
            float a = 0.f;
            for (int c = 0; c < 128; ++c) a += w1_q[t * 128 + c];
            float cv = 0.f, ci = 0.f;
            for (int c = 0; c < 64; ++c) { cv += w1_vi[t * 64 + c]; ci += w1_ir[t * 64 + c]; }
            Ad[t] = a; Cv[t] = cv; Ci[t] = ci; Bq[t] = b1_q[t];
        }
        __syncthreads();
        if (t == 0) {
            float av = 0, gv = 0, ai = 0, gi = 0;
            for (int d = 0; d < 8; ++d) {
                av += Ad[d] * Cv[d]; gv += Bq[d] * Cv[d];
                ai += Ad[d] * Ci[d]; gi += Bq[d] * Ci[d];
            }
            scal[0] = av; scal[1] = gv; scal[2] = ai; scal[3] = gi;
        }
    }
}

// k4: per block: stage s, sobel-recompute e_att -> elds + min/max, eq per
// m-tile. Main loop: 8 chunks of 512, double-buffered V in LDS; 16 waves =
// (h: chunk K-quarter) x (wvt: 4 m-tiles of 16 rows), each wave R9-shaped
// (4 independent n0 iters per chunk). Epilogue: 4-way h-reduce via LDS.
#define CH 512
#define NCH 8
__global__ __launch_bounds__(1024) void k4_attn(
        const float* __restrict__ s, const float* __restrict__ scal,
        const float* __restrict__ wsx_vi, const float* __restrict__ wsy_vi,
        const float* __restrict__ wsx_q,  const float* __restrict__ wsy_q,
        const float* __restrict__ wsx_ir, const float* __restrict__ wsy_ir,
        const __hip_bfloat16* __restrict__ Vc, float* __restrict__ out) {
    __shared__ __align__(16) char smem[147456];   // vbuf[2][64KB] + elds 16KB
    __shared__ float mm[32];
    char* vbuf0 = smem;
    char* vbuf1 = smem + 65536;
    float* elds = (float*)(smem + 131072);        // e_att[4096]
    const int mt = blockIdx.x;    // spatial row (64 m-rows per block)
    const int bw = blockIdx.y;    // b*2+which
    const int b = bw >> 1, which = bw & 1;
    const int amod = which ? 0 : 1;
    const float* wsxa = amod ? wsx_ir : wsx_vi;
    const float* wsya = amod ? wsy_ir : wsy_vi;
    const float alpha = scal[which ? 0 : 2];
    const float gamma = scal[which ? 1 : 3];
    const short* Vg = (const short*)(Vc + (size_t)(bw * 64) * 4096);

    const int tid = threadIdx.x;
    const int wvw = tid >> 6, lane = tid & 63;
    const int h = wvw >> 2, wvt = wvw & 3;       // chunk K-quarter, m-tile
    const int col = lane & 15, g = lane >> 4;

    // ---- phase A: stage s[b][2][4096] into vbuf0 --------------------------
    float* sld = (float*)vbuf0;
    const float* sg = s + (size_t)(b * 2) * 4096;
    #pragma unroll
    for (int k = 0; k < 8; ++k) { int i = tid + k * 1024; sld[i] = sg[i]; }
    __syncthreads();

    // ---- phase B: e_att field + min/max; eq for own m-tile ----------------
    float mn = 3.0e38f, mx = 0.f;
    {
        const float* sa = sld + amod * 4096;
        #pragma unroll
        for (int k2 = 0; k2 < 4; ++k2) {
            int n = tid + k2 * 1024;
            int hh = n >> 6, ww = n & 63;
            float gx = 0.f, gy = 0.f;
            #pragma unroll
            for (int di = 0; di < 3; ++di)
                #pragma unroll
                for (int dj = 0; dj < 3; ++dj) {
                    int r = hh + di - 1, c2 = ww + dj - 1;
                    bool in = (r >= 0) & (r < 64) & (c2 >= 0) & (c2 < 64);
                    float v = in ? sa[r * 64 + c2] : 0.f;
                    int kk = di * 3 + dj;
                    gx = fmaf(v, wsxa[kk], gx);
                    gy = fmaf(v, wsya[kk], gy);
                }
            float ev = fabsf(gx) + fabsf(gy);
            elds[n] = ev;
            mn = fminf(mn, ev); mx = fmaxf(mx, ev);
        }
    }
    float eq;
    {
        int ww = wvt * 16 + col;
        float gx = 0.f, gy = 0.f;
        #pragma unroll
        for (int di = 0; di < 3; ++di)
            #pragma unroll
            for (int dj = 0; dj < 3; ++dj) {
                int r = mt + di - 1, c2 = ww + dj - 1;
                bool in = (r >= 0) & (r < 64) & (c2 >= 0) & (c2 < 64);
                float v = in ? (sld[r * 64 + c2] + sld[4096 + r * 64 + c2]) : 0.f;
                int kk = di * 3 + dj;
                gx = fmaf(v, wsx_q[kk], gx);
                gy = fmaf(v, wsy_q[kk], gy);
            }
        eq = fabsf(gx) + fabsf(gy);
    }
    #pragma unroll
    for (int o = 32; o; o >>= 1) {
        mn = fminf(mn, __shfl_xor(mn, o));
        mx = fmaxf(mx, __shfl_xor(mx, o));
    }
    if (lane == 0) { mm[wvw] = mn; mm[16 + wvw] = mx; }
    __syncthreads();             // closes sld reads too
    float emn = mm[0], emx = mm[16];
    #pragma unroll
    for (int w = 1; w < 16; ++w) {
        emn = fminf(emn, mm[w]); emx = fmaxf(emx, mm[16 + w]);
    }
    const float L2E = 1.4426950408889634f;
    const float t  = alpha * eq + gamma;
    const float t2 = t * L2E;
    const float nM2 = -((t > 0.f) ? t * emx : t * emn) * L2E;

    // ---- phase C: stage V chunk 0 (overwrites sld) ------------------------
    #pragma unroll
    for (int k = 0; k < 4; ++k) {
        int id = tid + k * 1024;
        int c = id >> 6, ss = id & 63;
        bf16x8 v = *(const bf16x8*)(Vg + c * 4096 + ss * 8);
        *(bf16x8*)(vbuf0 + c * 1024 + ((ss * 16) ^ ((c & 31) << 4))) = v;
    }
    __syncthreads();

    f32x4 acc[4] = {};
    f32x4 accz = {};
    bf16x8 ones;
    #pragma unroll
    for (int j = 0; j < 8; ++j) ones[j] = (short)0x3F80;

    for (int ck = 0; ck < NCH; ++ck) {
        bf16x8 stg[4];
        const bool pf = (ck + 1 < NCH);
        if (pf) {
            const short* src = Vg + (ck + 1) * CH;
            #pragma unroll
            for (int k = 0; k < 4; ++k) {
                int id = tid + k * 1024;
                int c = id >> 6, ss = id & 63;
                stg[k] = *(const bf16x8*)(src + c * 4096 + ss * 8);
            }
        }
        const char* vb = (ck & 1) ? vbuf1 : vbuf0;
        const float* el = elds + ck * CH;
        #pragma unroll
        for (int j = 0; j < 4; ++j) {
            const int n0 = (h * 4 + j) * 32;
            bf16x8 af[4];
            #pragma unroll
            for (int cb = 0; cb < 4; ++cb) {
                int row = cb * 16 + col;
                int byte = row * 1024 + (((n0 + g * 8) * 2) ^ ((row & 31) << 4));
                af[cb] = *(const bf16x8*)(vb + byte);
            }
            f32x4 e0 = *(const f32x4*)(el + n0 + g * 8);
            f32x4 e1 = *(const f32x4*)(el + n0 + g * 8 + 4);
            bf16v8 pb;
            #pragma unroll
            for (int q = 0; q < 4; ++q) {
                float g0 = fmaf(e0[q], t2, nM2);
                float g1 = fmaf(e1[q], t2, nM2);
                pb[q]     = (__bf16)EXP2(g0);
                pb[q + 4] = (__bf16)EXP2(g1);
            }
            bf16x8 bfrag = __builtin_bit_cast(bf16x8, pb);
            #pragma unroll
            for (int cb = 0; cb < 4; ++cb)
                acc[cb] = __builtin_amdgcn_mfma_f32_16x16x32_bf16(af[cb], bfrag, acc[cb], 0, 0, 0);
            accz = __builtin_amdgcn_mfma_f32_16x16x32_bf16(ones, bfrag, accz, 0, 0, 0);
        }
        __syncthreads();
        if (pf) {
            char* wb = (ck & 1) ? vbuf0 : vbuf1;
            #pragma unroll
            for (int k = 0; k < 4; ++k) {
                int id = tid + k * 1024;
                int c = id >> 6, ss = id & 63;
                *(bf16x8*)(wb + c * 1024 + ((ss * 16) ^ ((c & 31) << 4))) = stg[k];
            }
            __syncthreads();
        }
    }

    // ---- epilogue: 4-way h-reduce via LDS (stride 17 floats) --------------
    float* rbuf = (float*)vbuf0;   // [h-1][wvt][lane][17] = 52 KB
    if (h > 0) {
        int base = (((h - 1) * 4 + wvt) * 64 + lane) * 17;
        #pragma unroll
        for (int cb = 0; cb < 4; ++cb)
            *(f32x4*)(rbuf + base + cb * 4) = acc[cb];
        rbuf[base + 16] = accz[0];
    }
    __syncthreads();
    if (h == 0) {
        float z = accz[0];
        #pragma unroll
        for (int src = 0; src < 3; ++src) {
            int sb = ((src * 4 + wvt) * 64 + lane) * 17;
            #pragma unroll
            for (int cb = 0; cb < 4; ++cb)
                acc[cb] += *(const f32x4*)(rbuf + sb + cb * 4);
            z += rbuf[sb + 16];
        }
        float inv = 1.0f / z;
        int m = mt * 64 + wvt * 16 + col;
        float* ob = out + which * (2 * 64 * 4096) + b * (64 * 4096) + m;
        #pragma unroll
        for (int cb = 0; cb < 4; ++cb) {
            int c = cb * 16 + g * 4;
            #pragma unroll
            for (int r = 0; r < 4; ++r) ob[(c + r) * 4096] = acc[cb][r] * inv;
        }
    }
}

extern "C" void kernel_launch(void* const* d_in, const int* in_sizes, int n_in,
                              void* d_out, int out_size, void* d_ws, size_t ws_size,
                              hipStream_t stream) {
    const float* vi     = (const float*)d_in[0];
    const float* ir     = (const float*)d_in[1];
    const float* wsx_vi = (const float*)d_in[2];
    const float* wsy_vi = (const float*)d_in[3];
    const float* w1_vi  = (const float*)d_in[4];
    const float* wsx_q  = (const float*)d_in[6];
    const float* wsy_q  = (const float*)d_in[7];
    const float* w1_q   = (const float*)d_in[8];
    const float* b1_q   = (const float*)d_in[9];
    const float* wsx_ir = (const float*)d_in[10];
    const float* wsy_ir = (const float*)d_in[11];
    const float* w1_ir  = (const float*)d_in[12];
    const float* wv_vi  = (const float*)d_in[14];
    const float* bv_vi  = (const float*)d_in[15];
    const float* wv_ir  = (const float*)d_in[16];
    const float* bv_ir  = (const float*)d_in[17];
    (void)in_sizes; (void)n_in; (void)out_size;

    char* ws = (char*)d_ws;
    float* scal = (float*)ws;                              // 64 B used
    float* s    = (float*)(ws + 1280);                     // 64 KB [4][4096]
    __hip_bfloat16* Vc = (__hip_bfloat16*)(ws + 1280 + 65536);  // 2 MB
    float* out = (float*)d_out;
    (void)ws_size;

    kP_prep<<<dim3(257), 256, 0, stream>>>(vi, ir, w1_vi, w1_q, b1_q, w1_ir,
                                           wv_vi, bv_vi, wv_ir, bv_ir, s, scal, Vc);
    k4_attn<<<dim3(64, 4), 1024, 0, stream>>>(s, scal, wsx_vi, wsy_vi, wsx_q, wsy_q,
                                              wsx_ir, wsy_ir, Vc, out);
}

// Round 14
// 30.846 us; speedup vs baseline: 2.1890x; 1.0506x over previous
//
#include <hip/hip_runtime.h>
#include <hip/hip_bf16.h>

typedef __attribute__((ext_vector_type(8))) short bf16x8;
typedef __attribute__((ext_vector_type(8))) __bf16 bf16v8;
typedef __attribute__((ext_vector_type(4))) float f32x4;
typedef __attribute__((ext_vector_type(4))) int   i32x4;

#if __has_builtin(__builtin_amdgcn_exp2f)
#define EXP2(x) __builtin_amdgcn_exp2f(x)
#else
#define EXP2(x) exp2f(x)
#endif

// async 16B global -> LDS DMA. LDS dest is wave-uniform base + lane*16;
// swizzle is applied on the per-lane GLOBAL slot index instead (m173 pattern),
// producing a bit-identical LDS image to the old reg-staged XOR layout.
__device__ __forceinline__ void async_copy16(const void* g, void* l) {
    __builtin_amdgcn_global_load_lds(
        (const __attribute__((address_space(1))) unsigned int*)g,
        (__attribute__((address_space(3))) unsigned int*)l, 16, 0, 0);
}

// ---------------------------------------------------------------------------
// B=2, C=64, H=W=64, N=4096, dk=8.
// Sobel weights broadcast over [C,C,3,3] -> conv = conv(chansum). Keys/queries
// affine in scalar field e[n]; attn row m = softmax_n(t_m*e[n]),
// t_m = alpha*eq[m]+gamma; row max = t*e_max (t>0) else t*e_min.
// 2 graph nodes: kP (value GEMM + s byproduct + alpha/gamma) ->
//                k4 (per-block sobel recompute + full-K attention).
// R6/R10: cross-block fences / grid.sync cost ~2x pipeline (cross-XCD).
// R11: inline-asm exp/cvt dodge the hazard recognizer -> NaN; use builtins.
// R12: MT-per-wave regressed; keep one-m-tile-per-wave shape.
// R13: 16 waves (4/SIMD) won. R14: V staging via global_load_lds DMA with
// pre-swizzled global source -> 1 barrier/chunk, no VGPR round-trip.
// ---------------------------------------------------------------------------

// kP: blocks 0..255 value GEMM (V[c,n] = W x + b) + s byproduct;
//     block 256: alpha/gamma reduction.
__global__ __launch_bounds__(256) void kP_prep(
    const float* __restrict__ vi, const float* __restrict__ ir,
    const float* __restrict__ w1_vi, const float* __restrict__ w1_q,
    const float* __restrict__ b1_q,  const float* __restrict__ w1_ir,
    const float* __restrict__ wv_vi, const float* __restrict__ bv_vi,
    const float* __restrict__ wv_ir, const float* __restrict__ bv_ir,
    float* __restrict__ s, float* __restrict__ scal,
    __hip_bfloat16* __restrict__ Vc) {
    const int t = threadIdx.x;
    if (blockIdx.x < 256) {
        __shared__ __align__(16) char wlds[64 * 128];   // 64x64 bf16 swizzled
        const int bm = blockIdx.x >> 6, nt = blockIdx.x & 63;
        const int b = bm >> 1, mod = bm & 1;
        const float* wv = mod ? wv_ir : wv_vi;
        const float* bv = mod ? bv_ir : bv_vi;
        const float* x = (mod ? ir : vi) + b * (64 * 4096);
        {
            const float* src = wv + t * 16;
            int row = t >> 2, colb = (t & 3) * 32;
            bf16v8 lo8, hi8;
            #pragma unroll
            for (int j = 0; j < 8; ++j) {
                lo8[j] = (__bf16)src[j];
                hi8[j] = (__bf16)src[8 + j];
            }
            int sw = (row & 7) << 4;
            *(i32x4*)(wlds + row * 128 + (colb ^ sw)) = __builtin_bit_cast(i32x4, lo8);
            *(i32x4*)(wlds + row * 128 + ((colb + 16) ^ sw)) = __builtin_bit_cast(i32x4, hi8);
        }
        __syncthreads();
        const int wvid = t >> 6, lane = t & 63;
        const int col = lane & 15, g = lane >> 4;
        const int n = nt * 64 + wvid * 16 + col;
        bf16x8 afr[4][2];
        #pragma unroll
        for (int cb = 0; cb < 4; ++cb) {
            int row = cb * 16 + col;
            int sw = (row & 7) << 4;
            #pragma unroll
            for (int ks = 0; ks < 2; ++ks)
                afr[cb][ks] = *(const bf16x8*)(wlds + row * 128 + ((ks * 64 + g * 16) ^ sw));
        }
        float ssum = 0.f;
        bf16x8 bfr[2];
        #pragma unroll
        for (int ks = 0; ks < 2; ++ks) {
            const float* xr = x + (ks * 32 + g * 8) * 4096 + n;
            bf16v8 pb;
            #pragma unroll
            for (int j = 0; j < 8; ++j) {
                float v = xr[j * 4096];
                ssum += v;
                pb[j] = (__bf16)v;
            }
            bfr[ks] = __builtin_bit_cast(bf16x8, pb);
        }
        ssum += __shfl_xor(ssum, 16);
        ssum += __shfl_xor(ssum, 32);
        if (lane < 16) s[bm * 4096 + nt * 64 + wvid * 16 + lane] = ssum;

        f32x4 acc[4];
        #pragma unroll
        for (int cb = 0; cb < 4; ++cb)
            #pragma unroll
            for (int r = 0; r < 4; ++r) acc[cb][r] = bv[cb * 16 + g * 4 + r];
        #pragma unroll
        for (int ks = 0; ks < 2; ++ks)
            #pragma unroll
            for (int cb = 0; cb < 4; ++cb)
                acc[cb] = __builtin_amdgcn_mfma_f32_16x16x32_bf16(afr[cb][ks], bfr[ks], acc[cb], 0, 0, 0);
        __hip_bfloat16* outp = Vc + (size_t)(bm * 64) * 4096 + n;
        #pragma unroll
        for (int cb = 0; cb < 4; ++cb)
            #pragma unroll
            for (int r = 0; r < 4; ++r)
                outp[(cb * 16 + g * 4 + r) * 4096] = __float2bfloat16(acc[cb][r]);
    } else {
        __shared__ float Ad[8], Cv[8], Ci[8], Bq[8];
        if (t < 8) {
            float a = 0.f;
            for (int c = 0; c < 128; ++c) a += w1_q[t * 128 + c];
            float cv = 0.f, ci = 0.f;
            for (int c = 0; c < 64; ++c) { cv += w1_vi[t * 64 + c]; ci += w1_ir[t * 64 + c]; }
            Ad[t] = a; Cv[t] = cv; Ci[t] = ci; Bq[t] = b1_q[t];
        }
        __syncthreads();
        if (t == 0) {
            float av = 0, gv = 0, ai = 0, gi = 0;
            for (int d = 0; d < 8; ++d) {
                av += Ad[d] * Cv[d]; gv += Bq[d] * Cv[d];
                ai += Ad[d] * Ci[d]; gi += Bq[d] * Ci[d];
            }
            scal[0] = av; scal[1] = gv; scal[2] = ai; scal[3] = gi;
        }
    }
}

// k4: per block: stage s, sobel-recompute e_att -> elds + min/max, eq per
// m-tile. Main loop: 8 chunks of 512, double-buffered V in LDS via async
// global_load_lds DMA (issued at top of iter, drained by the single barrier);
// 16 waves = (h: chunk K-quarter) x (wvt: 4 m-tiles). 4-way h-reduce epilogue.
#define CH 512
#define NCH 8
__global__ __launch_bounds__(1024) void k4_attn(
        const float* __restrict__ s, const float* __restrict__ scal,
        const float* __restrict__ wsx_vi, const float* __restrict__ wsy_vi,
        const float* __restrict__ wsx_q,  const float* __restrict__ wsy_q,
        const float* __restrict__ wsx_ir, const float* __restrict__ wsy_ir,
        const __hip_bfloat16* __restrict__ Vc, float* __restrict__ out) {
    __shared__ __align__(16) char smem[147456];   // vbuf[2][64KB] + elds 16KB
    __shared__ float mm[32];
    char* vbuf0 = smem;
    char* vbuf1 = smem + 65536;
    float* elds = (float*)(smem + 131072);        // e_att[4096]
    const int mt = blockIdx.x;    // spatial row (64 m-rows per block)
    const int bw = blockIdx.y;    // b*2+which
    const int b = bw >> 1, which = bw & 1;
    const int amod = which ? 0 : 1;
    const float* wsxa = amod ? wsx_ir : wsx_vi;
    const float* wsya = amod ? wsy_ir : wsy_vi;
    const float alpha = scal[which ? 0 : 2];
    const float gamma = scal[which ? 1 : 3];
    const short* Vg = (const short*)(Vc + (size_t)(bw * 64) * 4096);

    const int tid = threadIdx.x;
    const int wvw = tid >> 6, lane = tid & 63;
    const int h = wvw >> 2, wvt = wvw & 3;       // chunk K-quarter, m-tile
    const int col = lane & 15, g = lane >> 4;

    // ---- phase A: stage s[b][2][4096] into vbuf0 --------------------------
    float* sld = (float*)vbuf0;
    const float* sg = s + (size_t)(b * 2) * 4096;
    #pragma unroll
    for (int k = 0; k < 8; ++k) { int i = tid + k * 1024; sld[i] = sg[i]; }
    __syncthreads();

    // ---- phase B: e_att field + min/max; eq for own m-tile ----------------
    float mn = 3.0e38f, mx = 0.f;
    {
        const float* sa = sld + amod * 4096;
        #pragma unroll
        for (int k2 = 0; k2 < 4; ++k2) {
            int n = tid + k2 * 1024;
            int hh = n >> 6, ww = n & 63;
            float gx = 0.f, gy = 0.f;
            #pragma unroll
            for (int di = 0; di < 3; ++di)
                #pragma unroll
                for (int dj = 0; dj < 3; ++dj) {
                    int r = hh + di - 1, c2 = ww + dj - 1;
                    bool in = (r >= 0) & (r < 64) & (c2 >= 0) & (c2 < 64);
                    float v = in ? sa[r * 64 + c2] : 0.f;
                    int kk = di * 3 + dj;
                    gx = fmaf(v, wsxa[kk], gx);
                    gy = fmaf(v, wsya[kk], gy);
                }
            float ev = fabsf(gx) + fabsf(gy);
            elds[n] = ev;
            mn = fminf(mn, ev); mx = fmaxf(mx, ev);
        }
    }
    float eq;
    {
        int ww = wvt * 16 + col;
        float gx = 0.f, gy = 0.f;
        #pragma unroll
        for (int di = 0; di < 3; ++di)
            #pragma unroll
            for (int dj = 0; dj < 3; ++dj) {
                int r = mt + di - 1, c2 = ww + dj - 1;
                bool in = (r >= 0) & (r < 64) & (c2 >= 0) & (c2 < 64);
                float v = in ? (sld[r * 64 + c2] + sld[4096 + r * 64 + c2]) : 0.f;
                int kk = di * 3 + dj;
                gx = fmaf(v, wsx_q[kk], gx);
                gy = fmaf(v, wsy_q[kk], gy);
            }
        eq = fabsf(gx) + fabsf(gy);
    }
    #pragma unroll
    for (int o = 32; o; o >>= 1) {
        mn = fminf(mn, __shfl_xor(mn, o));
        mx = fmaxf(mx, __shfl_xor(mx, o));
    }
    if (lane == 0) { mm[wvw] = mn; mm[16 + wvw] = mx; }
    __syncthreads();             // closes sld reads too
    float emn = mm[0], emx = mm[16];
    #pragma unroll
    for (int w = 1; w < 16; ++w) {
        emn = fminf(emn, mm[w]); emx = fmaxf(emx, mm[16 + w]);
    }
    const float L2E = 1.4426950408889634f;
    const float t  = alpha * eq + gamma;
    const float t2 = t * L2E;
    const float nM2 = -((t > 0.f) ? t * emx : t * emn) * L2E;

    // ---- phase C: DMA chunk 0 into vbuf0 (rows wvw, wvw+16, +32, +48) -----
    #pragma unroll
    for (int k = 0; k < 4; ++k) {
        int c = wvw + k * 16;
        async_copy16(Vg + c * 4096 + ((lane ^ (c & 31)) * 8), vbuf0 + c * 1024);
    }
    __syncthreads();             // drains DMA (compiler emits vmcnt(0))

    f32x4 acc[4] = {};
    f32x4 accz = {};
    bf16x8 ones;
    #pragma unroll
    for (int j = 0; j < 8; ++j) ones[j] = (short)0x3F80;

    for (int ck = 0; ck < NCH; ++ck) {
        if (ck + 1 < NCH) {      // issue next-chunk DMA; lands in other buffer
            char* wb = ((ck + 1) & 1) ? vbuf1 : vbuf0;
            const short* src = Vg + (ck + 1) * CH;
            #pragma unroll
            for (int k = 0; k < 4; ++k) {
                int c = wvw + k * 16;
                async_copy16(src + c * 4096 + ((lane ^ (c & 31)) * 8), wb + c * 1024);
            }
        }
        const char* vb = (ck & 1) ? vbuf1 : vbuf0;
        const float* el = elds + ck * CH;
        #pragma unroll
        for (int j = 0; j < 4; ++j) {
            const int n0 = (h * 4 + j) * 32;
            bf16x8 af[4];
            #pragma unroll
            for (int cb = 0; cb < 4; ++cb) {
                int row = cb * 16 + col;
                int byte = row * 1024 + (((n0 + g * 8) * 2) ^ ((row & 31) << 4));
                af[cb] = *(const bf16x8*)(vb + byte);
            }
            f32x4 e0 = *(const f32x4*)(el + n0 + g * 8);
            f32x4 e1 = *(const f32x4*)(el + n0 + g * 8 + 4);
            bf16v8 pb;
            #pragma unroll
            for (int q = 0; q < 4; ++q) {
                float g0 = fmaf(e0[q], t2, nM2);
                float g1 = fmaf(e1[q], t2, nM2);
                pb[q]     = (__bf16)EXP2(g0);
                pb[q + 4] = (__bf16)EXP2(g1);
            }
            bf16x8 bfrag = __builtin_bit_cast(bf16x8, pb);
            #pragma unroll
            for (int cb = 0; cb < 4; ++cb)
                acc[cb] = __builtin_amdgcn_mfma_f32_16x16x32_bf16(af[cb], bfrag, acc[cb], 0, 0, 0);
            accz = __builtin_amdgcn_mfma_f32_16x16x32_bf16(ones, bfrag, accz, 0, 0, 0);
        }
        __syncthreads();         // joins waves AND drains next-chunk DMA
    }

    // ---- epilogue: 4-way h-reduce via LDS (stride 17 floats) --------------
    float* rbuf = (float*)vbuf0;   // [h-1][wvt][lane][17] = 52 KB
    if (h > 0) {
        int base = (((h - 1) * 4 + wvt) * 64 + lane) * 17;
        #pragma unroll
        for (int cb = 0; cb < 4; ++cb)
            *(f32x4*)(rbuf + base + cb * 4) = acc[cb];
        rbuf[base + 16] = accz[0];
    }
    __syncthreads();
    if (h == 0) {
        float z = accz[0];
        #pragma unroll
        for (int src = 0; src < 3; ++src) {
            int sb = ((src * 4 + wvt) * 64 + lane) * 17;
            #pragma unroll
            for (int cb = 0; cb < 4; ++cb)
                acc[cb] += *(const f32x4*)(rbuf + sb + cb * 4);
            z += rbuf[sb + 16];
        }
        float inv = 1.0f / z;
        int m = mt * 64 + wvt * 16 + col;
        float* ob = out + which * (2 * 64 * 4096) + b * (64 * 4096) + m;
        #pragma unroll
        for (int cb = 0; cb < 4; ++cb) {
            int c = cb * 16 + g * 4;
            #pragma unroll
            for (int r = 0; r < 4; ++r) ob[(c + r) * 4096] = acc[cb][r] * inv;
        }
    }
}

extern "C" void kernel_launch(void* const* d_in, const int* in_sizes, int n_in,
                              void* d_out, int out_size, void* d_ws, size_t ws_size,
                              hipStream_t stream) {
    const float* vi     = (const float*)d_in[0];
    const float* ir     = (const float*)d_in[1];
    const float* wsx_vi = (const float*)d_in[2];
    const float* wsy_vi = (const float*)d_in[3];
    const float* w1_vi  = (const float*)d_in[4];
    const float* wsx_q  = (const float*)d_in[6];
    const float* wsy_q  = (const float*)d_in[7];
    const float* w1_q   = (const float*)d_in[8];
    const float* b1_q   = (const float*)d_in[9];
    const float* wsx_ir = (const float*)d_in[10];
    const float* wsy_ir = (const float*)d_in[11];
    const float* w1_ir  = (const float*)d_in[12];
    const float* wv_vi  = (const float*)d_in[14];
    const float* bv_vi  = (const float*)d_in[15];
    const float* wv_ir  = (const float*)d_in[16];
    const float* bv_ir  = (const float*)d_in[17];
    (void)in_sizes; (void)n_in; (void)out_size;

    char* ws = (char*)d_ws;
    float* scal = (float*)ws;                              // 64 B used
    float* s    = (float*)(ws + 1280);                     // 64 KB [4][4096]
    __hip_bfloat16* Vc = (__hip_bfloat16*)(ws + 1280 + 65536);  // 2 MB
    float* out = (float*)d_out;
    (void)ws_size;

    kP_prep<<<dim3(257), 256, 0, stream>>>(vi, ir, w1_vi, w1_q, b1_q, w1_ir,
                                           wv_vi, bv_vi, wv_ir, bv_ir, s, scal, Vc);
    k4_attn<<<dim3(64, 4), 1024, 0, stream>>>(s, scal, wsx_vi, wsy_vi, wsx_q, wsy_q,
                                              wsx_ir, wsy_ir, Vc, out);
}